// Round 6
// baseline (70.581 us; speedup 1.0000x reference)
//
#include <hip/hip_runtime.h>
#include <hip/hip_bf16.h>
#include <math.h>

#define CIN    1024
#define S_TOT  400
#define COUT   255
#define NCH    85
#define NIMG   64
#define SB     16            // spatial columns per block
#define NI     2             // images per block
#define NTHR   256

// LDS: X panel for one K-half: [NI][SB s][64 g] x 16B = 32768 B
#define LDS_BYTES 32768

typedef __attribute__((ext_vector_type(8))) short bf16x8;
typedef __attribute__((ext_vector_type(4))) float f32x4;

// 16B store with 4B alignment guarantee (out row stride 85 floats)
struct __attribute__((aligned(4))) f4u { float x, y, z, w; };

// X LDS granule (img, s_local, g_local). Row = s (1024B stride); XOR-swizzle by
// (s>>1) so stage writes (s-pairs share xor) and frag reads (16 s rows, 2 per
// slot) are both conflict-free — same pattern as rounds 3-5 (measured 0).
__device__ __forceinline__ int xOff2(int img, int s, int gl) {
    return img * 16384 + (s << 10) + ((gl << 4) ^ (((s >> 1) & 7) << 4));
}

__device__ __forceinline__ unsigned pk2(float a, float b) {
    __hip_bfloat162 h;
    h.x = __float2bfloat16(a);
    h.y = __float2bfloat16(b);
    return *reinterpret_cast<unsigned*>(&h);
}

__device__ __forceinline__ float sigmoidf_(float v) {
    return 1.0f / (1.0f + expf(-v));
}

// ---- pre-kernel: W fp32 -> bf16, granule-major [g][co][8k] (512 KiB) ----
__global__ __launch_bounds__(256) void w_pre2(const float* __restrict__ w,
                                              unsigned short* __restrict__ wbf) {
    int gidx = blockIdx.x * 256 + threadIdx.x;
    int co = gidx & 255;          // fastest -> coalesced 16B writes
    int g  = gidx >> 8;           // 0..127 (k = g*8)
    union { unsigned short u[8]; bf16x8 v; } pk;
    if (co < COUT) {
        const float* src = w + (size_t)co * CIN + g * 8;
        #pragma unroll
        for (int j = 0; j < 8; ++j) {
            __hip_bfloat16 h = __float2bfloat16(src[j]);
            pk.u[j] = *reinterpret_cast<unsigned short*>(&h);
        }
    } else {
        #pragma unroll
        for (int j = 0; j < 8; ++j) pk.u[j] = 0;    // pad co=255
    }
    *reinterpret_cast<bf16x8*>((char*)wbf + ((size_t)(g << 8) + co) * 16) = pk.v;
}

// ---- main: block = 16s x 2img, all 255 co; A from L2, B from LDS; 3 barriers ----
__global__ __launch_bounds__(NTHR, 4) void yolo_mfma2(
    const float* __restrict__ xin,
    const unsigned short* __restrict__ wbf,
    const float* __restrict__ bias,
    float* __restrict__ out)
{
    __shared__ __align__(16) char smem[LDS_BYTES];

    const int sb  = blockIdx.x * SB;
    const int n0  = blockIdx.y * NI;
    const int tid = threadIdx.x;
    const int lane = tid & 63;
    const int wid  = tid >> 6;
    const int llo  = lane & 15;
    const int lhi  = lane >> 4;

    f32x4 acc[4][NI] = {};

    for (int h = 0; h < 2; ++h) {
        if (h) __syncthreads();            // protect smem from in-flight reads

        // ---- stage X K-half h: 1024 units (img, gl, s-pair), 4 per thread ----
        #pragma unroll
        for (int p = 0; p < 4; ++p) {
            int unit = p * 256 + tid;
            int img  = unit >> 9;          // 0..1
            int gl   = (unit >> 3) & 63;   // k-granule within half
            int sp   = unit & 7;           // s-pair
            const float* src = xin
                + ((size_t)(n0 + img) * CIN + h * 512 + gl * 8) * S_TOT
                + sb + 2 * sp;
            float2 cu[8];
            #pragma unroll
            for (int j = 0; j < 8; ++j) cu[j] = *(const float2*)(src + j * S_TOT);
            union { unsigned u[4]; bf16x8 v; } r0, r1;
            #pragma unroll
            for (int j = 0; j < 4; ++j) {
                r0.u[j] = pk2(cu[2 * j].x, cu[2 * j + 1].x);
                r1.u[j] = pk2(cu[2 * j].y, cu[2 * j + 1].y);
            }
            *(bf16x8*)(smem + xOff2(img, 2 * sp,     gl)) = r0.v;
            *(bf16x8*)(smem + xOff2(img, 2 * sp + 1, gl)) = r1.v;
        }
        __syncthreads();

        // ---- 16 barrier-free MFMA K-steps; A straight from L2-resident wbf ----
        #pragma unroll 4
        for (int kk = 0; kk < 16; ++kk) {
            const int gA = (h * 16 + kk) * 4 + lhi;   // global k-granule
            const int gl = kk * 4 + lhi;              // LDS k-granule
            bf16x8 b[NI];
            #pragma unroll
            for (int im = 0; im < NI; ++im)
                b[im] = *(bf16x8*)(smem + xOff2(im, llo, gl));
            #pragma unroll
            for (int mi = 0; mi < 4; ++mi) {
                const int co = wid * 64 + mi * 16 + llo;
                bf16x8 a = *(const bf16x8*)((const char*)wbf
                                            + ((size_t)(gA << 8) + co) * 16);
                #pragma unroll
                for (int im = 0; im < NI; ++im)
                    acc[mi][im] = __builtin_amdgcn_mfma_f32_16x16x32_bf16(
                        a, b[im], acc[mi][im], 0, 0, 0);
            }
        }
    }

    // ---- fused YOLO epilogue: 16B stores of 4 consecutive co ----
    const float anchW[3] = {116.0f, 156.0f, 373.0f};
    const float anchH[3] = {90.0f, 198.0f, 326.0f};

    #pragma unroll
    for (int mi = 0; mi < 4; ++mi) {
        const int co0 = wid * 64 + mi * 16 + lhi * 4;
        const int aW  = co0 / NCH;
        const int c0  = co0 - aW * NCH;
        const bool whole = (c0 <= NCH - 4) && (co0 + 3 < COUT);
        float bv[4];
        #pragma unroll
        for (int r = 0; r < 4; ++r)
            bv[r] = (co0 + r < COUT) ? bias[co0 + r] : 0.0f;

        #pragma unroll
        for (int im = 0; im < NI; ++im) {
            const int n = n0 + im;
            const int s = sb + llo;
            const float sx = (float)(s % 20);
            const float sy = (float)(s / 20);
            if (whole) {
                float r4[4];
                #pragma unroll
                for (int r = 0; r < 4; ++r) {
                    const int c = c0 + r;
                    const float v = acc[mi][im][r] + bv[r];
                    float res;
                    if (c == 0)      res = (sigmoidf_(v) + sx) * 32.0f;
                    else if (c == 1) res = (sigmoidf_(v) + sy) * 32.0f;
                    else if (c == 2) res = expf(v) * anchW[aW];
                    else if (c == 3) res = expf(v) * anchH[aW];
                    else             res = sigmoidf_(v);
                    r4[r] = res;
                }
                f4u* p = (f4u*)(out + (size_t)n * 102000 + aW * 34000 + s * 85 + c0);
                f4u val = {r4[0], r4[1], r4[2], r4[3]};
                *p = val;
            } else {
                #pragma unroll
                for (int r = 0; r < 4; ++r) {
                    const int co = co0 + r;
                    if (co < COUT) {
                        const int a2 = co / NCH;
                        const int c  = co - a2 * NCH;
                        const float v = acc[mi][im][r] + bv[r];
                        float res;
                        if (c == 0)      res = (sigmoidf_(v) + sx) * 32.0f;
                        else if (c == 1) res = (sigmoidf_(v) + sy) * 32.0f;
                        else if (c == 2) res = expf(v) * anchW[a2];
                        else if (c == 3) res = expf(v) * anchH[a2];
                        else             res = sigmoidf_(v);
                        out[(size_t)n * 102000 + a2 * 34000 + s * 85 + c] = res;
                    }
                }
            }
        }
    }
}

extern "C" void kernel_launch(void* const* d_in, const int* in_sizes, int n_in,
                              void* d_out, int out_size, void* d_ws, size_t ws_size,
                              hipStream_t stream) {
    const float* xin  = (const float*)d_in[0];
    const float* w    = (const float*)d_in[1];
    const float* bias = (const float*)d_in[2];
    float* out = (float*)d_out;
    unsigned short* wbf = (unsigned short*)d_ws;   // 512 KiB granule-major W

    w_pre2<<<128, 256, 0, stream>>>(w, wbf);
    yolo_mfma2<<<dim3(S_TOT / SB, NIMG / NI), NTHR, 0, stream>>>(xin, wbf, bias, out);
}